// Round 1
// baseline (122.260 us; speedup 1.0000x reference)
//
#include <hip/hip_runtime.h>
#include <math.h>

#define NT 50      // num event types
#define ND 4       // num decays
#define NB 4       // batch
#define NN 2048    // events per batch
#define TI 256     // events per i-tile
#define JC 128     // j-chunk size
#define TILES (NN/TI)                 // 8
#define BLK_PER_B (TILES*(TILES+1))   // sum_k (2k+2) = 72
#define GRID_R (NB*BLK_PER_B)         // 288
#define CSTRIDE 52                    // padded ty-stride in LDS A
#define DSTRIDE (NT*CSTRIDE)          // 2600

__device__ __forceinline__ float softplus_stable(float x) {
    // matches jax.nn.softplus: max(x,0) + log1p(exp(-|x|))
    return fmaxf(x, 0.0f) + log1pf(__expf(-fabsf(x)));
}

// ---------------- Kernel 1: pairwise excitation, tiled triangular ----------------
// block = (b, i-tile k, j-chunk jc), jc in [0, 2k+2)
// thread t owns event i = k*256 + t; loops over 128 j's of its chunk.
// Factorization: exp(-w(ti-tj)) = F_i[d] * E_j[d] with
//   F_i[d] = exp(-w_d (t_i - T0)), E_j[d] = exp(+w_d (t_j - T0)), T0 = t_{j0}.
// Inner loop: 4 LDS reads + 4 FMAs per pair, no transcendentals.
__global__ __launch_bounds__(256) void rates_kernel(
        const float* __restrict__ times,
        const int*   __restrict__ types,
        const float* __restrict__ alpha_p,
        const float* __restrict__ beta_p,
        float* __restrict__ acc) {
    __shared__ float  As[ND * DSTRIDE];   // softplus(alpha), layout [d][c][ty], 41.6 KB
    __shared__ float4 E4s[JC];
    __shared__ int    cofs[JC];           // c_j * CSTRIDE (prescaled)
    __shared__ float  wls[ND];

    int tid = threadIdx.x;
    int bb  = blockIdx.x / BLK_PER_B;
    int m   = blockIdx.x % BLK_PER_B;
    int k = 0;
    while (m >= (k + 1) * (k + 2)) ++k;   // tile k occupies m in [k^2+k, (k+1)(k+2))
    int jc   = m - k * (k + 1);
    int base = bb * NN;
    int i    = (k << 8) + tid;
    int j0   = jc << 7;

    if (tid < ND) wls[tid] = softplus_stable(beta_p[tid]);
    __syncthreads();
    float w0 = wls[0], w1 = wls[1], w2 = wls[2], w3 = wls[3];

    // stage softplus(alpha) transposed: src t = ty*200 + c*4 + d  ->  As[d*2600 + c*52 + ty]
    for (int t = tid; t < NT * NT * ND; t += 256) {
        int ty  = t / (NT * ND);
        int rem = t - ty * (NT * ND);
        int c = rem >> 2, d = rem & 3;
        As[d * DSTRIDE + c * CSTRIDE + ty] = softplus_stable(alpha_p[t]);
    }

    float T0 = times[base + j0];
    if (tid < JC) {
        int j    = j0 + tid;
        float tj = times[base + j];
        int   cj = types[base + j];
        cofs[tid] = cj * CSTRIDE;
        float dt = tj - T0;                      // >= 0, w*dt <= ~31: no overflow
        E4s[tid] = make_float4(__expf(w0 * dt), __expf(w1 * dt),
                               __expf(w2 * dt), __expf(w3 * dt));
    }
    float t_i = times[base + i];
    int   ty  = types[base + i];
    float ddt = t_i - T0;
    float F0 = __expf(-w0 * ddt), F1 = __expf(-w1 * ddt);
    float F2 = __expf(-w2 * ddt), F3 = __expf(-w3 * ddt);
    __syncthreads();

    // per-lane trip count enforces strict j < i (handles diagonal chunks uniformly)
    int jend = min(JC, i - j0);
    float a0 = 0.f, a1 = 0.f, a2 = 0.f, a3 = 0.f;
    #pragma unroll 4
    for (int jj = 0; jj < jend; ++jj) {
        float4 E = E4s[jj];                      // uniform LDS broadcast
        int idx  = cofs[jj] + ty;                // per-lane ty -> <=2-way bank alias (free)
        a0 = fmaf(As[idx              ], E.x, a0);
        a1 = fmaf(As[idx + 1 * DSTRIDE], E.y, a1);
        a2 = fmaf(As[idx + 2 * DSTRIDE], E.z, a2);
        a3 = fmaf(As[idx + 3 * DSTRIDE], E.w, a3);
    }
    if (jend > 0) {
        float partial = w0 * F0 * a0 + w1 * F1 * a1 + w2 * F2 * a2 + w3 * F3 * a3;
        atomicAdd(&acc[base + i], partial);      // <=16 contributions per event
    }
}

// ---------------- Kernel 2: finalize (log-rate, compensator, batch reduce) ----------------
// grid = NB*NN/256 = 32 blocks; block handles 256 consecutive events (same batch).
__global__ __launch_bounds__(256) void finalize_kernel(
        const float* __restrict__ times,
        const int*   __restrict__ types,
        const float* __restrict__ mask,
        const float* __restrict__ t0v,
        const float* __restrict__ t1v,
        const float* __restrict__ mu_p,
        const float* __restrict__ alpha_p,
        const float* __restrict__ beta_p,
        const float* __restrict__ acc,
        float* __restrict__ out) {
    __shared__ float cls[NT * ND];   // colsum[c][d] = sum_k softplus(alpha[k][c][d])
    __shared__ float wls[ND];
    __shared__ float red[8];

    int tid = threadIdx.x;
    int e   = blockIdx.x * 256 + tid;
    int b   = e >> 11;

    if (tid < NT * ND) {
        float s = 0.f;
        for (int kk = 0; kk < NT; ++kk)
            s += softplus_stable(alpha_p[kk * (NT * ND) + tid]);
        cls[tid] = s;
    }
    if (tid >= 200 && tid < 200 + ND) wls[tid - 200] = softplus_stable(beta_p[tid - 200]);

    // baseline compensator term, once per batch (first block of each batch, wave 0)
    if ((blockIdx.x & 7) == 0 && tid < 64) {
        float sp = (tid < NT) ? softplus_stable(mu_p[tid]) : 0.f;
        #pragma unroll
        for (int off = 32; off > 0; off >>= 1) sp += __shfl_down(sp, off, 64);
        if (tid == 0) atomicAdd(&out[NB + b], (t1v[b] - t0v[b]) * sp);
    }
    __syncthreads();
    float w0 = wls[0], w1 = wls[1], w2 = wls[2], w3 = wls[3];

    int   ty   = types[e];
    float mk   = mask[e];
    float rate = softplus_stable(mu_p[ty]) + acc[e];
    float ll   = logf(rate + 1e-8f) * mk;

    float tt = t1v[b] - times[e];
    float4 cv = *(const float4*)&cls[ty * 4];
    float cp = (cv.x * (1.f - __expf(-w0 * tt)) + cv.y * (1.f - __expf(-w1 * tt)) +
                cv.z * (1.f - __expf(-w2 * tt)) + cv.w * (1.f - __expf(-w3 * tt))) * mk;

    #pragma unroll
    for (int off = 32; off > 0; off >>= 1) {
        ll += __shfl_down(ll, off, 64);
        cp += __shfl_down(cp, off, 64);
    }
    int lane = tid & 63, wid = tid >> 6;
    if (lane == 0) { red[wid] = ll; red[4 + wid] = cp; }
    __syncthreads();
    if (tid == 0) {
        atomicAdd(&out[b],      red[0] + red[1] + red[2] + red[3]);
        atomicAdd(&out[NB + b], red[4] + red[5] + red[6] + red[7]);
    }
}

extern "C" void kernel_launch(void* const* d_in, const int* in_sizes, int n_in,
                              void* d_out, int out_size, void* d_ws, size_t ws_size,
                              hipStream_t stream) {
    const float* times   = (const float*)d_in[0];
    const int*   types   = (const int*)  d_in[1];
    const float* mask    = (const float*)d_in[2];
    const float* t0      = (const float*)d_in[3];
    const float* t1      = (const float*)d_in[4];
    const float* mu_p    = (const float*)d_in[5];
    const float* alpha_p = (const float*)d_in[6];
    const float* beta_p  = (const float*)d_in[7];
    float* out = (float*)d_out;
    float* acc = (float*)d_ws;   // NB*NN floats

    hipMemsetAsync(acc, 0, NB * NN * sizeof(float), stream);
    hipMemsetAsync(out, 0, 2 * NB * sizeof(float), stream);
    rates_kernel<<<GRID_R, 256, 0, stream>>>(times, types, alpha_p, beta_p, acc);
    finalize_kernel<<<NB * NN / 256, 256, 0, stream>>>(times, types, mask, t0, t1,
                                                       mu_p, alpha_p, beta_p, acc, out);
}

// Round 2
// 90.964 us; speedup vs baseline: 1.3441x; 1.3441x over previous
//
#include <hip/hip_runtime.h>
#include <math.h>

#define NT 50      // num event types
#define ND 4       // num decays
#define NB 4       // batch
#define NN 2048    // events per batch
#define TI 32      // events per tile (one block per tile)
#define SUBS 8     // threads per event
#define TILES (NN/TI)          // 64
#define GRID (NB*TILES)        // 256 blocks

__device__ __forceinline__ float softplus_stable(float x) {
    // matches jax.nn.softplus: max(x,0) + log1p(exp(-|x|))
    return fmaxf(x, 0.0f) + log1pf(__expf(-fabsf(x)));
}

// One block per (batch, tile of 32 events). 256 threads = 32 events x 8 subs.
// Factorization: exp(-w_d(t_i - t_j)) = F_i[d] * E_j[d],
//   F_i[d] = exp(-w_d(t_i - T0)) <= 1,  E_j[d] = exp(+w_d(t_j - T0)) <= 1 for j < tile
//   (T0 = tile start time; times sorted).
// Far field (j < tile0) collapses by type:  sum_c Ahat[ty_i][c][d] * S[c][d],
//   S[c][d] = sum_{j<tile0, c_j=c} E_j[d]   -- 200-FMA dot per event, O(N) pairs gone.
// Intra-tile (<=31 pairs/event) done pairwise. Compensator + loglik fused here too.
__global__ __launch_bounds__(256) void hawkes_kernel(
        const float* __restrict__ times,
        const int*   __restrict__ types,
        const float* __restrict__ mask,
        const float* __restrict__ t0v,
        const float* __restrict__ t1v,
        const float* __restrict__ mu_p,
        const float* __restrict__ alpha_p,
        const float* __restrict__ beta_p,
        float* __restrict__ out) {
    __shared__ float4 At4[NT * NT];   // [c][ty] -> float4 over d ; 40000 B
    __shared__ float4 S4[NT];         // far-field type-binned sums   ; 800 B
    __shared__ float4 cls4[NT];       // colsum[c][d] for compensator ; 800 B
    __shared__ float4 E4s[TI];        // intra-tile E factors         ; 512 B
    __shared__ int    ctile[TI];      // c_j * NT (premultiplied)     ; 128 B
    __shared__ float  wls[4];
    __shared__ float  redA[8];

    int t     = threadIdx.x;
    int b     = blockIdx.x >> 6;          // TILES = 64
    int k     = blockIdx.x & 63;
    int tile0 = k * TI;
    int base  = b * NN;
    int il    = t >> 3;                   // local event index 0..31
    int sub   = t & 7;
    int i     = tile0 + il;
    int e     = base + i;

    if (t < ND) wls[t] = softplus_stable(beta_p[t]);
    if (t < NT) S4[t] = make_float4(0.f, 0.f, 0.f, 0.f);
    __syncthreads();
    float w0 = wls[0], w1 = wls[1], w2 = wls[2], w3 = wls[3];
    float T0 = times[base + tile0];

    // ---- stage softplus(alpha) as At4[c*NT + ty] = Ahat[ty][c][0..3] ----
    for (int q = t; q < NT * NT; q += 256) {
        float4 a = ((const float4*)alpha_p)[q];     // alpha[ty][c][0..3], coalesced
        a.x = softplus_stable(a.x); a.y = softplus_stable(a.y);
        a.z = softplus_stable(a.z); a.w = softplus_stable(a.w);
        int ty = q / NT, c = q - ty * NT;
        At4[c * NT + ty] = a;
    }
    // ---- far-field type-binned sums S[c][d] over j < tile0 ----
    for (int j = t; j < tile0; j += 256) {
        float tj = times[base + j];
        int   cj = types[base + j];
        float dt = tj - T0;                         // <= 0  ->  E <= 1
        float* sp = (float*)&S4[cj];
        atomicAdd(sp + 0, __expf(w0 * dt));
        atomicAdd(sp + 1, __expf(w1 * dt));
        atomicAdd(sp + 2, __expf(w2 * dt));
        atomicAdd(sp + 3, __expf(w3 * dt));
    }
    // ---- intra-tile E factors ----
    if (t < TI) {
        int j = tile0 + t;
        float dt = times[base + j] - T0;            // >= 0, tiny tile span
        E4s[t] = make_float4(__expf(w0 * dt), __expf(w1 * dt),
                             __expf(w2 * dt), __expf(w3 * dt));
        ctile[t] = types[base + j] * NT;
    }
    __syncthreads();

    // ---- colsum[c][d] = sum_ty Ahat[ty][c][d]  (compensator) ----
    if (t < NT * ND) {
        int c = t >> 2, d = t & 3;
        const float* col = (const float*)&At4[c * NT];
        float s = 0.f;
        for (int ty = 0; ty < NT; ++ty) s += col[ty * 4 + d];
        ((float*)&cls4[c])[d] = s;
    }

    // ---- per-event excitation ----
    float ti_ = times[e];
    int   ty  = types[e];
    float ddt = ti_ - T0;
    float F0 = __expf(-w0 * ddt), F1 = __expf(-w1 * ddt);
    float F2 = __expf(-w2 * ddt), F3 = __expf(-w3 * ddt);

    float a0 = 0.f, a1 = 0.f, a2 = 0.f, a3 = 0.f;
    if (tile0 > 0) {
        for (int c = sub; c < NT; c += SUBS) {      // far-field dot, split 8 ways
            float4 A = At4[c * NT + ty];
            float4 S = S4[c];
            a0 = fmaf(A.x, S.x, a0); a1 = fmaf(A.y, S.y, a1);
            a2 = fmaf(A.z, S.z, a2); a3 = fmaf(A.w, S.w, a3);
        }
    }
    for (int jj = sub; jj < il; jj += SUBS) {       // intra-tile pairs (j < i strict)
        float4 A = At4[ctile[jj] + ty];
        float4 E = E4s[jj];
        a0 = fmaf(A.x, E.x, a0); a1 = fmaf(A.y, E.y, a1);
        a2 = fmaf(A.z, E.z, a2); a3 = fmaf(A.w, E.w, a3);
    }
    float p = w0 * F0 * a0 + w1 * F1 * a1 + w2 * F2 * a2 + w3 * F3 * a3;
    p += __shfl_xor(p, 1, 64);
    p += __shfl_xor(p, 2, 64);
    p += __shfl_xor(p, 4, 64);
    __syncthreads();                                // cls4 ready

    // ---- per-event epilogue (sub 0 only), then block reduction ----
    float ll = 0.f, cp = 0.f;
    if (sub == 0) {
        float mk   = mask[e];
        float rate = softplus_stable(mu_p[ty]) + p;
        ll = logf(rate + 1e-8f) * mk;
        float tt = t1v[b] - ti_;
        float4 cs = cls4[ty];
        cp = (cs.x * (1.f - __expf(-w0 * tt)) + cs.y * (1.f - __expf(-w1 * tt)) +
              cs.z * (1.f - __expf(-w2 * tt)) + cs.w * (1.f - __expf(-w3 * tt))) * mk;
    }
    #pragma unroll
    for (int off = 8; off < 64; off <<= 1) {
        ll += __shfl_xor(ll, off, 64);
        cp += __shfl_xor(cp, off, 64);
    }
    int lane = t & 63, wid = t >> 6;
    if (lane == 0) { redA[wid] = ll; redA[4 + wid] = cp; }
    __syncthreads();
    if (t == 0) {
        atomicAdd(&out[b],      redA[0] + redA[1] + redA[2] + redA[3]);
        atomicAdd(&out[NB + b], redA[4] + redA[5] + redA[6] + redA[7]);
    }
    // baseline compensator (t1-t0)*sum(mhat): once per batch (k==0 block, wave 0)
    if (k == 0 && t < 64) {
        float sp = (t < NT) ? softplus_stable(mu_p[t]) : 0.f;
        #pragma unroll
        for (int off = 32; off > 0; off >>= 1) sp += __shfl_down(sp, off, 64);
        if (t == 0) atomicAdd(&out[NB + b], (t1v[b] - t0v[b]) * sp);
    }
}

extern "C" void kernel_launch(void* const* d_in, const int* in_sizes, int n_in,
                              void* d_out, int out_size, void* d_ws, size_t ws_size,
                              hipStream_t stream) {
    const float* times   = (const float*)d_in[0];
    const int*   types   = (const int*)  d_in[1];
    const float* mask    = (const float*)d_in[2];
    const float* t0      = (const float*)d_in[3];
    const float* t1      = (const float*)d_in[4];
    const float* mu_p    = (const float*)d_in[5];
    const float* alpha_p = (const float*)d_in[6];
    const float* beta_p  = (const float*)d_in[7];
    float* out = (float*)d_out;

    hipMemsetAsync(out, 0, 2 * NB * sizeof(float), stream);
    hawkes_kernel<<<GRID, 256, 0, stream>>>(times, types, mask, t0, t1,
                                            mu_p, alpha_p, beta_p, out);
}